// Round 21
// baseline (206.469 us; speedup 1.0000x reference)
//
#include <hip/hip_runtime.h>
#include <hip/hip_fp16.h>

#define NB 64
#define NS 512
#define NH 1024
#define NITERS 10

// log2 domain: -log2(512) = -9 exactly; f2 = 10*t*log2(e)
#define LOG2_INV_NS (-9.0f)
#define LOG2E 1.4426950408889634f

using half8 = _Float16 __attribute__((ext_vector_type(8)));
using f32x4 = float __attribute__((ext_vector_type(4)));

// ---------------------------------------------------------------------------
// Fused GEMM (R16 main loop verbatim): batched cosine scores, f16 out.
// Epilogue: S store + partial row sums of exp2(F2*S - 9) (iter-1 u step).
__global__ __launch_bounds__(512) void gemm_fused(
    const float* __restrict__ x, const float* __restrict__ y,
    _Float16* __restrict__ Sh, float* __restrict__ upartG) {
  __shared__ _Float16 As[2][256][72];
  __shared__ _Float16 Bs[2][256][72];
  __shared__ float invA[256], invB[256];
  __shared__ float upartL[4][256];

  int blk = blockIdx.x;
  int b = blk & 63;
  int tile = blk >> 6;
  int tm = (tile >> 1) * 256, tn = (tile & 1) * 256;
  int tid = threadIdx.x;
  int wid = tid >> 6, lane = tid & 63;
  int wr = (wid >> 2) * 128;
  int wc = (wid & 3) * 64;
  int fr = lane & 15, fq = lane >> 4;

  int srow = tid >> 1;
  int skh = (tid & 1) * 16;
  const float* xb = x + ((size_t)b * NS + tm + srow) * NH + skh;
  const float* yb = y + ((size_t)b * NS + tn + srow) * NH + skh;

  f32x4 acc[8][4] = {};
  float4 rx[4], ry[4];
  float sqx = 0.f, sqy = 0.f;

#define GLOAD(K0)                                                     \
  do {                                                                \
    const float4* px = (const float4*)(xb + (K0));                    \
    const float4* py = (const float4*)(yb + (K0));                    \
    rx[0] = px[0]; rx[1] = px[1]; rx[2] = px[2]; rx[3] = px[3];       \
    ry[0] = py[0]; ry[1] = py[1]; ry[2] = py[2]; ry[3] = py[3];       \
  } while (0)

#define CAST_WRITE(BUF, COL)                                          \
  do {                                                                \
    alignas(16) _Float16 ta[16];                                      \
    alignas(16) _Float16 tb[16];                                      \
    _Pragma("unroll") for (int j = 0; j < 4; ++j) {                   \
      float4 v = rx[j];                                               \
      ta[4 * j + 0] = (_Float16)v.x; ta[4 * j + 1] = (_Float16)v.y;   \
      ta[4 * j + 2] = (_Float16)v.z; ta[4 * j + 3] = (_Float16)v.w;   \
      sqx += v.x * v.x + v.y * v.y + v.z * v.z + v.w * v.w;           \
    }                                                                 \
    _Pragma("unroll") for (int j = 0; j < 4; ++j) {                   \
      float4 v = ry[j];                                               \
      tb[4 * j + 0] = (_Float16)v.x; tb[4 * j + 1] = (_Float16)v.y;   \
      tb[4 * j + 2] = (_Float16)v.z; tb[4 * j + 3] = (_Float16)v.w;   \
      sqy += v.x * v.x + v.y * v.y + v.z * v.z + v.w * v.w;           \
    }                                                                 \
    *(half8*)&As[BUF][srow][(COL) + skh + 0] = *(half8*)&ta[0];       \
    *(half8*)&As[BUF][srow][(COL) + skh + 8] = *(half8*)&ta[8];       \
    *(half8*)&Bs[BUF][srow][(COL) + skh + 0] = *(half8*)&tb[0];       \
    *(half8*)&Bs[BUF][srow][(COL) + skh + 8] = *(half8*)&tb[8];       \
  } while (0)

  GLOAD(0);
  CAST_WRITE(0, 0);
  GLOAD(32);
  CAST_WRITE(0, 32);
  GLOAD(64);
  asm volatile("s_waitcnt lgkmcnt(0)" ::: "memory");
  __builtin_amdgcn_sched_barrier(0);
  __builtin_amdgcn_s_barrier();
  __builtin_amdgcn_sched_barrier(0);

  for (int s = 0; s < 16; ++s) {
    int cur = s & 1;
    {
      half8 bf[4];
#pragma unroll
      for (int j = 0; j < 4; ++j)
        bf[j] = *(const half8*)&Bs[cur][wc + 16 * j + fr][8 * fq];
#pragma unroll
      for (int i = 0; i < 8; ++i) {
        half8 af = *(const half8*)&As[cur][wr + 16 * i + fr][8 * fq];
#pragma unroll
        for (int j = 0; j < 4; ++j)
          acc[i][j] = __builtin_amdgcn_mfma_f32_16x16x32_f16(af, bf[j], acc[i][j], 0, 0, 0);
      }
    }
    if (s < 15) {
      CAST_WRITE(cur ^ 1, 0);
      GLOAD((s + 1) * 64 + 32);
    }
    {
      half8 bf[4];
#pragma unroll
      for (int j = 0; j < 4; ++j)
        bf[j] = *(const half8*)&Bs[cur][wc + 16 * j + fr][32 + 8 * fq];
#pragma unroll
      for (int i = 0; i < 8; ++i) {
        half8 af = *(const half8*)&As[cur][wr + 16 * i + fr][32 + 8 * fq];
#pragma unroll
        for (int j = 0; j < 4; ++j)
          acc[i][j] = __builtin_amdgcn_mfma_f32_16x16x32_f16(af, bf[j], acc[i][j], 0, 0, 0);
      }
    }
    if (s < 15) {
      CAST_WRITE(cur ^ 1, 32);
      if (s < 14) GLOAD((s + 2) * 64);
    }
    asm volatile("s_waitcnt lgkmcnt(0)" ::: "memory");
    __builtin_amdgcn_sched_barrier(0);
    __builtin_amdgcn_s_barrier();
    __builtin_amdgcn_sched_barrier(0);
  }
#undef GLOAD
#undef CAST_WRITE

  sqx += __shfl_xor(sqx, 1, 64);
  sqy += __shfl_xor(sqy, 1, 64);
  if ((tid & 1) == 0) {
    invA[srow] = 1.0f / fmaxf(sqrtf(sqx), 1e-12f);
    invB[srow] = 1.0f / fmaxf(sqrtf(sqy), 1e-12f);
  }
  __syncthreads();

  // Epilogue: S = acc * invA[m] * invB[n] (f16 store) + partial row sums of
  // exp2(F2*S - 9). C/D layout: col = lane&15 (n), row = (lane>>4)*4 + reg.
  const float F2 = 10.0f * LOG2E;
  _Float16* Sb = Sh + (size_t)b * NS * NS;
#pragma unroll
  for (int i = 0; i < 8; ++i) {
    float rs[4] = {0.f, 0.f, 0.f, 0.f};
#pragma unroll
    for (int j = 0; j < 4; ++j) {
      int ccol = wc + 16 * j + fr;
      float ib = invB[ccol];
#pragma unroll
      for (int p = 0; p < 4; ++p) {
        int rr = wr + 16 * i + 4 * fq + p;
        float sval = acc[i][j][p] * invA[rr] * ib;
        Sb[(size_t)(tm + rr) * NS + tn + ccol] = (_Float16)sval;
        rs[p] += exp2f(fmaf(F2, sval, LOG2_INV_NS));
      }
    }
#pragma unroll
    for (int mask = 1; mask <= 8; mask <<= 1) {
#pragma unroll
      for (int p = 0; p < 4; ++p) rs[p] += __shfl_xor(rs[p], mask, 64);
    }
    if (fr == 0) {
#pragma unroll
      for (int p = 0; p < 4; ++p)
        upartL[wid & 3][wr + 16 * i + 4 * fq + p] = rs[p];
    }
  }
  __syncthreads();
  if (tid < 256) {
    float s = upartL[0][tid] + upartL[1][tid] + upartL[2][tid] + upartL[3][tid];
    upartG[(((size_t)b * 2 + (tile >> 1)) * 2 + (tile & 1)) * 256 + tid] = s;
  }
}

// ---------------------------------------------------------------------------
// P pass (iteration it), all duals in LOG2 domain.
__global__ __launch_bounds__(256) void p_kernel(
    const _Float16* __restrict__ Sh, const float* __restrict__ upartG,
    float* __restrict__ V, float* __restrict__ rowpart,
    float f2, float fnext2, int first, int last, float* __restrict__ outPart) {
  __shared__ float Ul[NS];
  __shared__ float partC[64][33];
  __shared__ float partD[64][33];
  __shared__ float redC[4][33];
  __shared__ float redD[4][33];
  __shared__ float Wl[32];
  __shared__ float partR[NS][5];

  int blk = blockIdx.x;
  int b = blk & 63;                 // blk%8 == b%8 (XCD-consistent with gemm)
  int ng = blk >> 6;                // 0..15, 32 cols each
  int t = threadIdx.x;
  int w = t >> 6, l = t & 63;

  // ---- prologue: U2 for this iteration ----
  if (first) {
    const float* up = upartG + (size_t)b * 1024;   // [mh][nh][256]
    float s0 = up[t] + up[256 + t];
    float s1 = up[512 + t] + up[768 + t];
    Ul[t] = LOG2_INV_NS - log2f(s0);
    Ul[t + 256] = LOG2_INV_NS - log2f(s1);
  } else {
    const float* rp = rowpart + (size_t)b * 16 * NS;
    float s0 = 0.f, s1 = 0.f;
#pragma unroll
    for (int k = 0; k < 16; ++k) {
      s0 += rp[k * NS + t];
      s1 += rp[k * NS + t + 256];
    }
    Ul[t] = LOG2_INV_NS - log2f(s0);
    Ul[t + 256] = LOG2_INV_NS - log2f(s1);
  }
  __syncthreads();

  // ---- load S panel into registers ----
  int oct = t & 3;
  int mc = t >> 2;                  // m-chunk (8 rows), 0..63
  const _Float16* Sbc = Sh + (size_t)b * NS * NS + (size_t)(mc * 8) * NS + ng * 32 + oct * 8;
  half8 hv[8];
#pragma unroll
  for (int i = 0; i < 8; ++i) hv[i] = *(const half8*)(Sbc + (size_t)i * NS);

  // ---- stage 1: col sums ----
  float c[8] = {}, d[8] = {};
  if (!last) {
#pragma unroll
    for (int i = 0; i < 8; ++i) {
      float um = Ul[mc * 8 + i];
#pragma unroll
      for (int e = 0; e < 8; ++e)
        c[e] += exp2f(fmaf(f2, (float)hv[i][e], um));
    }
  } else {
#pragma unroll
    for (int i = 0; i < 8; ++i) {
      float um = Ul[mc * 8 + i];
#pragma unroll
      for (int e = 0; e < 8; ++e) {
        float sv = (float)hv[i][e];
        float ev = exp2f(fmaf(f2, sv, um));
        c[e] += ev;
        d[e] = fmaf(sv, ev, d[e]);
      }
    }
  }
#pragma unroll
  for (int e = 0; e < 8; ++e) {
    partC[mc][oct * 8 + e] = c[e];
    if (last) partD[mc][oct * 8 + e] = d[e];
  }
  __syncthreads();
  {
    int ci = t & 31, seg = t >> 5;
    float cc = 0.f, dd = 0.f;
#pragma unroll
    for (int k = 0; k < 8; ++k) {
      cc += partC[seg * 8 + k][ci];
      if (last) dd += partD[seg * 8 + k][ci];
    }
    cc += __shfl_xor(cc, 32, 64);
    if (last) dd += __shfl_xor(dd, 32, 64);
    if (l < 32) { redC[w][l] = cc; if (last) redD[w][l] = dd; }
  }
  __syncthreads();
  if (t < 32) {
    float cc = redC[0][t] + redC[1][t] + redC[2][t] + redC[3][t];
    if (!last) {
      float vnew2 = LOG2_INV_NS - log2f(cc);
      int n = b * NS + ng * 32 + t;
      float vold2 = first ? 0.f : V[n];
      V[n] = vnew2;
      Wl[t] = 2.f * vnew2 - vold2;
    } else {
      float dd = redD[0][t] + redD[1][t] + redD[2][t] + redD[3][t];
      float r = dd / cc;
      r += __shfl_xor(r, 16, 64);
      r += __shfl_xor(r, 8, 64);
      r += __shfl_xor(r, 4, 64);
      r += __shfl_xor(r, 2, 64);
      r += __shfl_xor(r, 1, 64);
      if (t == 0) outPart[b * 16 + ng] = r * (1.0f / (float)NS);
    }
  }
  if (last) return;
  __syncthreads();

  // ---- stage 2: partial row sums for next iteration's u ----
  float wl[8];
#pragma unroll
  for (int e = 0; e < 8; ++e) wl[e] = Wl[oct * 8 + e];
#pragma unroll
  for (int i = 0; i < 8; ++i) {
    float s = 0.f;
#pragma unroll
    for (int e = 0; e < 8; ++e)
      s += exp2f(fmaf(fnext2, (float)hv[i][e], wl[e]));
    partR[mc * 8 + i][oct] = s;
  }
  __syncthreads();
  {
    float* rp = rowpart + ((size_t)b * 16 + ng) * NS;
    float q0 = partR[t][0] + partR[t][1] + partR[t][2] + partR[t][3];
    float q1 = partR[t + 256][0] + partR[t + 256][1] + partR[t + 256][2] + partR[t + 256][3];
    rp[t] = q0;
    rp[t + 256] = q1;
  }
}

// ---------------------------------------------------------------------------
// combine 16 partials per batch (deterministic)
__global__ void combine_kernel(const float* __restrict__ outPart, float* __restrict__ out) {
  int b = threadIdx.x;  // 64 threads
  float s = 0.f;
#pragma unroll
  for (int k = 0; k < 16; ++k) s += outPart[b * 16 + k];
  out[b] = s;
}

// ---------------------------------------------------------------------------
extern "C" void kernel_launch(void* const* d_in, const int* in_sizes, int n_in,
                              void* d_out, int out_size, void* d_ws, size_t ws_size,
                              hipStream_t stream) {
  (void)in_sizes; (void)n_in; (void)out_size; (void)ws_size;
  const float* x = (const float*)d_in[0];
  const float* y = (const float*)d_in[1];
  float* out = (float*)d_out;

  char* ws = (char*)d_ws;
  _Float16* Sh = (_Float16*)ws;                                // 32 MiB
  float* fregion = (float*)(ws + (size_t)NB * NS * NS * 2);
  float* V = fregion;                                          // 32768
  float* outPart = V + NB * NS;                                // 1024
  float* rowpart = outPart + 1024;                             // 64*16*512
  float* upartG = rowpart + (size_t)NB * 16 * NS;              // 64*4*256

  gemm_fused<<<256, 512, 0, stream>>>(x, y, Sh, upartG);

  for (int t = 1; t <= NITERS; ++t) {
    p_kernel<<<1024, 256, 0, stream>>>(Sh, upartG, V, rowpart,
                                       10.0f * LOG2E * (float)t,
                                       10.0f * LOG2E * (float)(t + 1),
                                       t == 1 ? 1 : 0, t == NITERS ? 1 : 0,
                                       outPart);
  }
  combine_kernel<<<1, 64, 0, stream>>>(outPart, out);
}

// Round 22
// 196.566 us; speedup vs baseline: 1.0504x; 1.0504x over previous
//
#include <hip/hip_runtime.h>
#include <hip/hip_fp16.h>

#define NB 64
#define NS 512
#define NH 1024
#define NITERS 10

// log2 domain: -log2(512) = -9 exactly; f2 = 10*t*log2(e)
#define LOG2_INV_NS (-9.0f)
#define LOG2E 1.4426950408889634f

using half8 = _Float16 __attribute__((ext_vector_type(8)));
using f32x4 = float __attribute__((ext_vector_type(4)));

// ---------------------------------------------------------------------------
// Fused GEMM (R16 verbatim — measured best ~107us): batched cosine scores,
// f16 out. 256x256 tile, 512 thr / 8 waves, BK=64, LDS double-buffer,
// raw s_barrier discipline, in-kernel row norms, epilogue normalization.
__global__ __launch_bounds__(512) void gemm_fused(
    const float* __restrict__ x, const float* __restrict__ y,
    _Float16* __restrict__ Sh) {
  __shared__ _Float16 As[2][256][72];
  __shared__ _Float16 Bs[2][256][72];
  __shared__ float invA[256], invB[256];

  int blk = blockIdx.x;
  int b = blk & 63;
  int tile = blk >> 6;
  int tm = (tile >> 1) * 256, tn = (tile & 1) * 256;
  int tid = threadIdx.x;
  int wid = tid >> 6, lane = tid & 63;
  int wr = (wid >> 2) * 128;
  int wc = (wid & 3) * 64;
  int fr = lane & 15, fq = lane >> 4;

  int srow = tid >> 1;
  int skh = (tid & 1) * 16;
  const float* xb = x + ((size_t)b * NS + tm + srow) * NH + skh;
  const float* yb = y + ((size_t)b * NS + tn + srow) * NH + skh;

  f32x4 acc[8][4] = {};
  float4 rx[4], ry[4];
  float sqx = 0.f, sqy = 0.f;

#define GLOAD(K0)                                                     \
  do {                                                                \
    const float4* px = (const float4*)(xb + (K0));                    \
    const float4* py = (const float4*)(yb + (K0));                    \
    rx[0] = px[0]; rx[1] = px[1]; rx[2] = px[2]; rx[3] = px[3];       \
    ry[0] = py[0]; ry[1] = py[1]; ry[2] = py[2]; ry[3] = py[3];       \
  } while (0)

#define CAST_WRITE(BUF, COL)                                          \
  do {                                                                \
    alignas(16) _Float16 ta[16];                                      \
    alignas(16) _Float16 tb[16];                                      \
    _Pragma("unroll") for (int j = 0; j < 4; ++j) {                   \
      float4 v = rx[j];                                               \
      ta[4 * j + 0] = (_Float16)v.x; ta[4 * j + 1] = (_Float16)v.y;   \
      ta[4 * j + 2] = (_Float16)v.z; ta[4 * j + 3] = (_Float16)v.w;   \
      sqx += v.x * v.x + v.y * v.y + v.z * v.z + v.w * v.w;           \
    }                                                                 \
    _Pragma("unroll") for (int j = 0; j < 4; ++j) {                   \
      float4 v = ry[j];                                               \
      tb[4 * j + 0] = (_Float16)v.x; tb[4 * j + 1] = (_Float16)v.y;   \
      tb[4 * j + 2] = (_Float16)v.z; tb[4 * j + 3] = (_Float16)v.w;   \
      sqy += v.x * v.x + v.y * v.y + v.z * v.z + v.w * v.w;           \
    }                                                                 \
    *(half8*)&As[BUF][srow][(COL) + skh + 0] = *(half8*)&ta[0];       \
    *(half8*)&As[BUF][srow][(COL) + skh + 8] = *(half8*)&ta[8];       \
    *(half8*)&Bs[BUF][srow][(COL) + skh + 0] = *(half8*)&tb[0];       \
    *(half8*)&Bs[BUF][srow][(COL) + skh + 8] = *(half8*)&tb[8];       \
  } while (0)

  GLOAD(0);
  CAST_WRITE(0, 0);
  GLOAD(32);
  CAST_WRITE(0, 32);
  GLOAD(64);
  asm volatile("s_waitcnt lgkmcnt(0)" ::: "memory");
  __builtin_amdgcn_sched_barrier(0);
  __builtin_amdgcn_s_barrier();
  __builtin_amdgcn_sched_barrier(0);

  for (int s = 0; s < 16; ++s) {
    int cur = s & 1;
    {
      half8 bf[4];
#pragma unroll
      for (int j = 0; j < 4; ++j)
        bf[j] = *(const half8*)&Bs[cur][wc + 16 * j + fr][8 * fq];
#pragma unroll
      for (int i = 0; i < 8; ++i) {
        half8 af = *(const half8*)&As[cur][wr + 16 * i + fr][8 * fq];
#pragma unroll
        for (int j = 0; j < 4; ++j)
          acc[i][j] = __builtin_amdgcn_mfma_f32_16x16x32_f16(af, bf[j], acc[i][j], 0, 0, 0);
      }
    }
    if (s < 15) {
      CAST_WRITE(cur ^ 1, 0);
      GLOAD((s + 1) * 64 + 32);
    }
    {
      half8 bf[4];
#pragma unroll
      for (int j = 0; j < 4; ++j)
        bf[j] = *(const half8*)&Bs[cur][wc + 16 * j + fr][32 + 8 * fq];
#pragma unroll
      for (int i = 0; i < 8; ++i) {
        half8 af = *(const half8*)&As[cur][wr + 16 * i + fr][32 + 8 * fq];
#pragma unroll
        for (int j = 0; j < 4; ++j)
          acc[i][j] = __builtin_amdgcn_mfma_f32_16x16x32_f16(af, bf[j], acc[i][j], 0, 0, 0);
      }
    }
    if (s < 15) {
      CAST_WRITE(cur ^ 1, 32);
      if (s < 14) GLOAD((s + 2) * 64);
    }
    asm volatile("s_waitcnt lgkmcnt(0)" ::: "memory");
    __builtin_amdgcn_sched_barrier(0);
    __builtin_amdgcn_s_barrier();
    __builtin_amdgcn_sched_barrier(0);
  }
#undef GLOAD
#undef CAST_WRITE

  sqx += __shfl_xor(sqx, 1, 64);
  sqy += __shfl_xor(sqy, 1, 64);
  if ((tid & 1) == 0) {
    invA[srow] = 1.0f / fmaxf(sqrtf(sqx), 1e-12f);
    invB[srow] = 1.0f / fmaxf(sqrtf(sqy), 1e-12f);
  }
  __syncthreads();

  _Float16* Sb = Sh + (size_t)b * NS * NS;
#pragma unroll
  for (int i = 0; i < 8; ++i)
#pragma unroll
    for (int j = 0; j < 4; ++j) {
      int rr = wr + 16 * i + 4 * fq;
      int cc = wc + 16 * j + fr;
      float ib = invB[cc];
#pragma unroll
      for (int p = 0; p < 4; ++p)
        Sb[(size_t)(tm + rr + p) * NS + tn + cc] =
            (_Float16)(acc[i][j][p] * invA[rr + p] * ib);
    }
}

// ---------------------------------------------------------------------------
// u_first (log2 domain): U2_1[m] = -9 - log2( sum_n exp2(f2*S - 9) ).
// Proven R19 structure; 2048 blocks.
__global__ __launch_bounds__(256) void u_first_kernel(
    const _Float16* __restrict__ Sh, float* __restrict__ U, float f2) {
  int blk = blockIdx.x;
  int bs = blk & 7, rest = blk >> 3;
  int rowgrp = rest & 31, bq = rest >> 5;
  int b = bq * 8 + bs;
  int t = threadIdx.x;
  int w = t >> 6, l = t & 63;
  int m0 = rowgrp * 16 + w * 4;
  const _Float16* Sb = Sh + ((size_t)b * NS + m0) * NS + 8 * l;
  float sum[4] = {0.f, 0.f, 0.f, 0.f};
#pragma unroll
  for (int k = 0; k < 4; ++k) {
    half8 hv = *(const half8*)(Sb + (size_t)k * NS);
#pragma unroll
    for (int e = 0; e < 8; ++e)
      sum[k] += exp2f(fmaf(f2, (float)hv[e], LOG2_INV_NS));
  }
#pragma unroll
  for (int o = 32; o; o >>= 1) {
#pragma unroll
    for (int k = 0; k < 4; ++k) sum[k] += __shfl_xor(sum[k], o, 64);
  }
  if (l == 0) {
#pragma unroll
    for (int k = 0; k < 4; ++k)
      U[b * NS + m0 + k] = LOG2_INV_NS - log2f(sum[k]);
  }
}

// ---------------------------------------------------------------------------
// P pass (iteration it), all duals in LOG2 domain (R21 verbatim except the
// first-iteration prologue reads U directly).
__global__ __launch_bounds__(256) void p_kernel(
    const _Float16* __restrict__ Sh, const float* __restrict__ Ufirst,
    float* __restrict__ V, float* __restrict__ rowpart,
    float f2, float fnext2, int first, int last, float* __restrict__ outPart) {
  __shared__ float Ul[NS];
  __shared__ float partC[64][33];
  __shared__ float partD[64][33];
  __shared__ float redC[4][33];
  __shared__ float redD[4][33];
  __shared__ float Wl[32];
  __shared__ float partR[NS][5];

  int blk = blockIdx.x;
  int b = blk & 63;                 // blk%8 == b%8 (XCD-consistent with gemm)
  int ng = blk >> 6;                // 0..15, 32 cols each
  int t = threadIdx.x;
  int w = t >> 6, l = t & 63;

  // ---- prologue: U2 for this iteration ----
  if (first) {
    Ul[t] = Ufirst[b * NS + t];
    Ul[t + 256] = Ufirst[b * NS + t + 256];
  } else {
    const float* rp = rowpart + (size_t)b * 16 * NS;
    float s0 = 0.f, s1 = 0.f;
#pragma unroll
    for (int k = 0; k < 16; ++k) {
      s0 += rp[k * NS + t];
      s1 += rp[k * NS + t + 256];
    }
    Ul[t] = LOG2_INV_NS - log2f(s0);
    Ul[t + 256] = LOG2_INV_NS - log2f(s1);
  }
  __syncthreads();

  // ---- load S panel into registers ----
  int oct = t & 3;
  int mc = t >> 2;                  // m-chunk (8 rows), 0..63
  const _Float16* Sbc = Sh + (size_t)b * NS * NS + (size_t)(mc * 8) * NS + ng * 32 + oct * 8;
  half8 hv[8];
#pragma unroll
  for (int i = 0; i < 8; ++i) hv[i] = *(const half8*)(Sbc + (size_t)i * NS);

  // ---- stage 1: col sums ----
  float c[8] = {}, d[8] = {};
  if (!last) {
#pragma unroll
    for (int i = 0; i < 8; ++i) {
      float um = Ul[mc * 8 + i];
#pragma unroll
      for (int e = 0; e < 8; ++e)
        c[e] += exp2f(fmaf(f2, (float)hv[i][e], um));
    }
  } else {
#pragma unroll
    for (int i = 0; i < 8; ++i) {
      float um = Ul[mc * 8 + i];
#pragma unroll
      for (int e = 0; e < 8; ++e) {
        float sv = (float)hv[i][e];
        float ev = exp2f(fmaf(f2, sv, um));
        c[e] += ev;
        d[e] = fmaf(sv, ev, d[e]);
      }
    }
  }
#pragma unroll
  for (int e = 0; e < 8; ++e) {
    partC[mc][oct * 8 + e] = c[e];
    if (last) partD[mc][oct * 8 + e] = d[e];
  }
  __syncthreads();
  {
    int ci = t & 31, seg = t >> 5;
    float cc = 0.f, dd = 0.f;
#pragma unroll
    for (int k = 0; k < 8; ++k) {
      cc += partC[seg * 8 + k][ci];
      if (last) dd += partD[seg * 8 + k][ci];
    }
    cc += __shfl_xor(cc, 32, 64);
    if (last) dd += __shfl_xor(dd, 32, 64);
    if (l < 32) { redC[w][l] = cc; if (last) redD[w][l] = dd; }
  }
  __syncthreads();
  if (t < 32) {
    float cc = redC[0][t] + redC[1][t] + redC[2][t] + redC[3][t];
    if (!last) {
      float vnew2 = LOG2_INV_NS - log2f(cc);
      int n = b * NS + ng * 32 + t;
      float vold2 = first ? 0.f : V[n];
      V[n] = vnew2;
      Wl[t] = 2.f * vnew2 - vold2;
    } else {
      float dd = redD[0][t] + redD[1][t] + redD[2][t] + redD[3][t];
      float r = dd / cc;
      r += __shfl_xor(r, 16, 64);
      r += __shfl_xor(r, 8, 64);
      r += __shfl_xor(r, 4, 64);
      r += __shfl_xor(r, 2, 64);
      r += __shfl_xor(r, 1, 64);
      if (t == 0) outPart[b * 16 + ng] = r * (1.0f / (float)NS);
    }
  }
  if (last) return;
  __syncthreads();

  // ---- stage 2: partial row sums for next iteration's u ----
  float wl[8];
#pragma unroll
  for (int e = 0; e < 8; ++e) wl[e] = Wl[oct * 8 + e];
#pragma unroll
  for (int i = 0; i < 8; ++i) {
    float s = 0.f;
#pragma unroll
    for (int e = 0; e < 8; ++e)
      s += exp2f(fmaf(fnext2, (float)hv[i][e], wl[e]));
    partR[mc * 8 + i][oct] = s;
  }
  __syncthreads();
  {
    float* rp = rowpart + ((size_t)b * 16 + ng) * NS;
    float q0 = partR[t][0] + partR[t][1] + partR[t][2] + partR[t][3];
    float q1 = partR[t + 256][0] + partR[t + 256][1] + partR[t + 256][2] + partR[t + 256][3];
    rp[t] = q0;
    rp[t + 256] = q1;
  }
}

// ---------------------------------------------------------------------------
// combine 16 partials per batch (deterministic)
__global__ void combine_kernel(const float* __restrict__ outPart, float* __restrict__ out) {
  int b = threadIdx.x;  // 64 threads
  float s = 0.f;
#pragma unroll
  for (int k = 0; k < 16; ++k) s += outPart[b * 16 + k];
  out[b] = s;
}

// ---------------------------------------------------------------------------
extern "C" void kernel_launch(void* const* d_in, const int* in_sizes, int n_in,
                              void* d_out, int out_size, void* d_ws, size_t ws_size,
                              hipStream_t stream) {
  (void)in_sizes; (void)n_in; (void)out_size; (void)ws_size;
  const float* x = (const float*)d_in[0];
  const float* y = (const float*)d_in[1];
  float* out = (float*)d_out;

  char* ws = (char*)d_ws;
  _Float16* Sh = (_Float16*)ws;                                // 32 MiB
  float* fregion = (float*)(ws + (size_t)NB * NS * NS * 2);
  float* U = fregion;                                          // 32768
  float* V = U + NB * NS;                                      // 32768
  float* outPart = V + NB * NS;                                // 1024
  float* rowpart = outPart + 1024;                             // 64*16*512

  gemm_fused<<<256, 512, 0, stream>>>(x, y, Sh);
  u_first_kernel<<<2048, 256, 0, stream>>>(Sh, U, 10.0f * LOG2E);

  for (int t = 1; t <= NITERS; ++t) {
    p_kernel<<<1024, 256, 0, stream>>>(Sh, U, V, rowpart,
                                       10.0f * LOG2E * (float)t,
                                       10.0f * LOG2E * (float)(t + 1),
                                       t == 1 ? 1 : 0, t == NITERS ? 1 : 0,
                                       outPart);
  }
  combine_kernel<<<1, 64, 0, stream>>>(outPart, out);
}